// Round 1
// 327.157 us; speedup vs baseline: 1.1503x; 1.1503x over previous
//
#include <hip/hip_runtime.h>
#include <hip/hip_bf16.h>

#define NN 100000
#define NE 1280000
#define DD 64
#define RSHIFT 9             // 512-node dst ranges
#define NRANGE 196           // ceil(NN/512)
#define NGROUPS (NN / 16)    // 6250
#define GG 1536              // persistent gemm grid (6 blocks/CU)

typedef __attribute__((ext_vector_type(8))) short bf16x8;
typedef __attribute__((ext_vector_type(4))) float f32x4;

static __device__ __forceinline__ unsigned short f2bf(float f) {
    __hip_bfloat16 h = __float2bfloat16(f);
    return *reinterpret_cast<unsigned short*>(&h);
}

// ---------------------------------------------------------------------------
// x (fp32) -> bf16 copy. Grid 6250 x 256, 4 elems/thread (exact: 6.4M).
// ---------------------------------------------------------------------------
__global__ __launch_bounds__(256) void f32_to_bf16_kernel(
    const float* __restrict__ in, unsigned short* __restrict__ out)
{
    int i = (blockIdx.x * 256 + threadIdx.x) * 4;
    float4 v = *(const float4*)(in + i);
    ushort4 o;
    o.x = f2bf(v.x); o.y = f2bf(v.y); o.z = f2bf(v.z); o.w = f2bf(v.w);
    *(ushort4*)(out + i) = o;
}

// ---------------------------------------------------------------------------
// Range histogram: count edges per 512-node dst range. LDS-staged.
// ---------------------------------------------------------------------------
__global__ __launch_bounds__(256) void hist2_kernel(
    const int* __restrict__ dst, int* __restrict__ rangeCnt)
{
    __shared__ int h[256];
    int tid = threadIdx.x;
    h[tid] = 0;
    __syncthreads();
    int e0 = blockIdx.x * 1024 + tid * 4;
    int4 d4 = *(const int4*)(dst + e0);
    atomicAdd(&h[d4.x >> RSHIFT], 1);
    atomicAdd(&h[d4.y >> RSHIFT], 1);
    atomicAdd(&h[d4.z >> RSHIFT], 1);
    atomicAdd(&h[d4.w >> RSHIFT], 1);
    __syncthreads();
    if (tid < NRANGE && h[tid]) atomicAdd(&rangeCnt[tid], h[tid]);
}

// ---------------------------------------------------------------------------
// Exclusive scan of 196 range counts -> rangeBase[197] + gcur (P1 cursors).
// ---------------------------------------------------------------------------
__global__ __launch_bounds__(256) void scan196_kernel(
    const int* __restrict__ rangeCnt, int* __restrict__ rangeBase,
    int* __restrict__ gcur, int* __restrict__ rowptr)
{
    __shared__ int sd[256];
    int tid = threadIdx.x;
    int v = (tid < NRANGE) ? rangeCnt[tid] : 0;
    sd[tid] = v;
    __syncthreads();
    for (int o = 1; o < 256; o <<= 1) {
        int t = (tid >= o) ? sd[tid - o] : 0;
        __syncthreads();
        sd[tid] += t;
        __syncthreads();
    }
    if (tid < NRANGE) { int ex = sd[tid] - v; rangeBase[tid] = ex; gcur[tid] = ex; }
    if (tid == 0) { rangeBase[NRANGE] = NE; rowptr[NN] = NE; }
}

// ---------------------------------------------------------------------------
// P1: coarse bin by dst range, block-synchronous LDS staging (grouped runs).
// Record packs: src (17b) | local-dst (9b @ bit17).
// ---------------------------------------------------------------------------
__global__ __launch_bounds__(256) void p1_bin_kernel(
    const int* __restrict__ src, const int* __restrict__ dst,
    const float* __restrict__ w, int* __restrict__ gcur,
    int2* __restrict__ ecoarse)
{
    __shared__ int2 stage[1024];
    __shared__ unsigned char sbkt[1024];
    __shared__ int cnt[256], ofs[256], gpos[256], sd[256];

    int tid = threadIdx.x;
    int e0 = blockIdx.x * 1024 + tid * 4;
    int4   s4 = *(const int4*)(src + e0);
    int4   d4 = *(const int4*)(dst + e0);
    float4 w4 = *(const float4*)(w + e0);

    cnt[tid] = 0;
    __syncthreads();

    int ss[4] = {s4.x, s4.y, s4.z, s4.w};
    int dd[4] = {d4.x, d4.y, d4.z, d4.w};
    float ww[4] = {w4.x, w4.y, w4.z, w4.w};
    int b[4], p[4];
#pragma unroll
    for (int i = 0; i < 4; ++i) {
        b[i] = dd[i] >> RSHIFT;
        p[i] = atomicAdd(&cnt[b[i]], 1);
    }
    __syncthreads();

    int cv = cnt[tid];
    sd[tid] = cv;
    __syncthreads();
    for (int o = 1; o < 256; o <<= 1) {
        int t = (tid >= o) ? sd[tid - o] : 0;
        __syncthreads();
        sd[tid] += t;
        __syncthreads();
    }
    ofs[tid] = sd[tid] - cv;
    if (tid < NRANGE && cv > 0) gpos[tid] = atomicAdd(&gcur[tid], cv);
    __syncthreads();

#pragma unroll
    for (int i = 0; i < 4; ++i) {
        int slot = ofs[b[i]] + p[i];
        stage[slot] = make_int2(ss[i] | ((dd[i] & 511) << 17), __float_as_int(ww[i]));
        sbkt[slot] = (unsigned char)b[i];
    }
    __syncthreads();

    for (int j = tid; j < 1024; j += 256) {
        int bb = sbkt[j];
        ecoarse[gpos[bb] + (j - ofs[bb])] = stage[j];
    }
}

// ---------------------------------------------------------------------------
// P2: per-range degree count + LDS scan -> rowptr, then place into the
// range's L2-resident ebuf window. Grid NRANGE (196), 2 nodes/thread.
// ---------------------------------------------------------------------------
__global__ __launch_bounds__(256) void p2_place_kernel(
    const int2* __restrict__ ecoarse, const int* __restrict__ rangeBase,
    int* __restrict__ rowptr, int2* __restrict__ ebuf)
{
    __shared__ int cnt[512];
    __shared__ int ssum[256];
    int r = blockIdx.x, tid = threadIdx.x;
    int beg = rangeBase[r], end = rangeBase[r + 1];

    cnt[tid] = 0; cnt[tid + 256] = 0;
    __syncthreads();

    for (int j = beg + tid; j < end; j += 256) {
        int2 rec = ecoarse[j];
        atomicAdd(&cnt[(rec.x >> 17) & 511], 1);
    }
    __syncthreads();

    int c0 = cnt[2 * tid], c1 = cnt[2 * tid + 1];
    int s = c0 + c1;
    ssum[tid] = s;
    __syncthreads();
    for (int o = 1; o < 256; o <<= 1) {
        int t = (tid >= o) ? ssum[tid - o] : 0;
        __syncthreads();
        ssum[tid] += t;
        __syncthreads();
    }
    int p0 = beg + ssum[tid] - s;
    int p1 = p0 + c0;

    int node0 = (r << RSHIFT) + 2 * tid;
    if (node0 < NN)     rowptr[node0]     = p0;
    if (node0 + 1 < NN) rowptr[node0 + 1] = p1;
    cnt[2 * tid] = p0; cnt[2 * tid + 1] = p1;
    __syncthreads();

    for (int j = beg + tid; j < end; j += 256) {
        int2 rec = ecoarse[j];
        int dl = (rec.x >> 17) & 511;
        int p = atomicAdd(&cnt[dl], 1);
        ebuf[p] = make_int2(rec.x & 0x1FFFF, rec.y);
    }
}

// ---------------------------------------------------------------------------
// CSR gather over bf16 rows -> bf16 agg. Wave per node.
// MLP-restructured: lane = (half, ch): ch = channel PAIR (u32 = 2 bf16),
// half = edge parity. One cooperative ebuf load stages <=64 edges in regs;
// (src,w) distributed by __shfl; 8 gather slots (16 edges) in flight per
// unrolled body, masked tail (w=0) instead of remainder loop.
// ---------------------------------------------------------------------------
__global__ __launch_bounds__(256) void csr_agg_bf16_kernel(
    const unsigned short* __restrict__ hb, const int* __restrict__ rowptr,
    const int2* __restrict__ ebuf, unsigned short* __restrict__ aggb)
{
    int lane = threadIdx.x & 63;
    int node = blockIdx.x * 4 + (threadIdx.x >> 6);
    int beg = __builtin_amdgcn_readfirstlane(rowptr[node]);
    int end = __builtin_amdgcn_readfirstlane(rowptr[node + 1]);
    int deg = end - beg;
    int half = lane >> 5;        // edge slot parity handled by this lane
    int ch = lane & 31;          // channel pair: channels 2ch, 2ch+1
    const unsigned int* __restrict__ hw = (const unsigned int*)hb;

    float aL0 = 0.f, aH0 = 0.f, aL1 = 0.f, aH1 = 0.f;

    for (int c = 0; c < deg; c += 64) {
        int rem = deg - c;
        int nsl = rem < 64 ? rem : 64;
        // stage up to 64 edges across lanes with ONE load instruction
        int idx = (lane < nsl) ? (c + lane) : c;
        int2 e = ebuf[beg + idx];
        float wt = (lane < nsl) ? __int_as_float(e.y) : 0.f;

        for (int s0 = 0; s0 < nsl; s0 += 16) {
#pragma unroll
            for (int i = 0; i < 8; ++i) {
                int slot = s0 + 2 * i + half;
                bool ok = slot < nsl;
                int sl = ok ? slot : 0;
                int sr = __shfl(e.x, sl);
                float w = __shfl(wt, sl);
                w = ok ? w : 0.f;
                unsigned v = hw[sr * 32 + ch];
                if (i & 1) {
                    aL1 = fmaf(w, __uint_as_float(v << 16), aL1);
                    aH1 = fmaf(w, __uint_as_float(v & 0xFFFF0000u), aH1);
                } else {
                    aL0 = fmaf(w, __uint_as_float(v << 16), aL0);
                    aH0 = fmaf(w, __uint_as_float(v & 0xFFFF0000u), aH0);
                }
            }
        }
    }

    float accL = aL0 + aL1, accH = aH0 + aH1;
    accL += __shfl_xor(accL, 32);
    accH += __shfl_xor(accH, 32);
    if (half == 0) {
        unsigned out = ((unsigned)f2bf(accH) << 16) | (unsigned)f2bf(accL);
        ((unsigned int*)aggb)[(size_t)node * 32 + ch] = out;
    }
}

// ---------------------------------------------------------------------------
// MFMA dual GEMM (persistent): out16[g*16..][n] = [aggb|hb] @ [Wrel;Wroot]
// + bias (+ReLU). A = 16x128 bf16 (per group), B = 128x64 bf16 (static).
// B fragments held in registers (loaded once); A staged to LDS in MFMA
// fragment order (double-buffered, 1 barrier/group); 4 MFMA/wave/group.
// Layouts (m89/m120-verified): A[m=lane&15][k=quad*8+j],
// B[k=quad*8+j][n=lane&15], D row=quad*4+reg col=lane&15.
// OUT32: store fp32 (layer 3) else bf16.
// ---------------------------------------------------------------------------
template <bool RELU, bool OUT32>
__global__ __launch_bounds__(256) void mfma_gemm_kernel(
    const unsigned short* __restrict__ aggb,
    const unsigned short* __restrict__ hb,
    const float* __restrict__ Wrel,
    const float* __restrict__ brel,
    const float* __restrict__ Wroot,
    void* __restrict__ outp)
{
    __shared__ __align__(16) unsigned short Ast[2][256][8];   // 8 KB

    int tid = threadIdx.x;
    int lane = tid & 63;
    int wv = tid >> 6;            // wave = N-tile (cols 16w..16w+16)
    int quad = lane >> 4;
    int m16 = lane & 15;
    int n = wv * 16 + m16;        // this lane's output column

    // ---- B fragments (static weights) into registers: 4 ksteps x 8 bf16
    bf16x8 bfrag[4];
#pragma unroll
    for (int t = 0; t < 4; ++t) {
#pragma unroll
        for (int j = 0; j < 8; ++j) {
            int k = t * 32 + quad * 8 + j;
            float wval = (k < 64) ? Wrel[k * 64 + n] : Wroot[(k - 64) * 64 + n];
            bfrag[t][j] = (short)f2bf(wval);
        }
    }
    float bias = brel[n];

    // staging role of this thread: kstep ts, row ms, col base c0 (8 bf16 = 16B)
    int ts = tid >> 6;
    int ls = tid & 63;
    int ms = ls & 15;
    int c0 = ts * 32 + (ls >> 4) * 8;
    bool fromAgg = (c0 < 64);
    int cOff = fromAgg ? c0 : (c0 - 64);

    int g = blockIdx.x;
    int buf = 0;
    while (g < NGROUPS) {
        // ---- stage A (16 rows x 128 k, bf16) in fragment order
        {
            size_t row = (size_t)g * 16 + ms;
            const unsigned short* sp = (fromAgg ? aggb : hb) + row * DD + cOff;
            *(uint4*)&Ast[buf][tid][0] = *(const uint4*)sp;
        }
        __syncthreads();

        // ---- 4 chained MFMAs over K=128
        f32x4 c = {0.f, 0.f, 0.f, 0.f};
#pragma unroll
        for (int t = 0; t < 4; ++t) {
            bf16x8 a = *(const bf16x8*)&Ast[buf][t * 64 + lane][0];
            c = __builtin_amdgcn_mfma_f32_16x16x32_bf16(a, bfrag[t], c, 0, 0, 0);
        }

        // ---- epilogue: bias (+ReLU), store
#pragma unroll
        for (int reg = 0; reg < 4; ++reg) {
            int row = quad * 4 + reg;
            size_t node = (size_t)g * 16 + row;
            float v = c[reg] + bias;
            if (RELU) v = fmaxf(v, 0.f);
            if (OUT32) ((float*)outp)[node * DD + n] = v;
            else       ((unsigned short*)outp)[node * DD + n] = f2bf(v);
        }
        g += GG;
        buf ^= 1;
    }
}

extern "C" void kernel_launch(void* const* d_in, const int* in_sizes, int n_in,
                              void* d_out, int out_size, void* d_ws, size_t ws_size,
                              hipStream_t stream)
{
    const float* x     = (const float*)d_in[0];
    const int*   ei    = (const int*)d_in[1];
    const float* w     = (const float*)d_in[2];
    const float* Wrel1 = (const float*)d_in[4];
    const float* brel1 = (const float*)d_in[5];
    const float* Wroot1= (const float*)d_in[6];
    const float* Wrel2 = (const float*)d_in[7];
    const float* brel2 = (const float*)d_in[8];
    const float* Wroot2= (const float*)d_in[9];
    const float* Wrel3 = (const float*)d_in[10];
    const float* brel3 = (const float*)d_in[11];
    const float* Wroot3= (const float*)d_in[12];

    float* out = (float*)d_out;

    // workspace: ebuf | region2 (ecoarse -> xb, after build) | aggb | hb | ints
    char* ws = (char*)d_ws;
    int2*  ebuf    = (int2*)ws;                       ws += (size_t)NE * 8;          // 10.24 MB
    int2*  ecoarse = (int2*)ws;
    unsigned short* xb = (unsigned short*)ws;         ws += (size_t)NN * DD * 2;     // 12.8 MB (>= ecoarse 10.24)
    unsigned short* aggb = (unsigned short*)ws;       ws += (size_t)NN * DD * 2;     // 12.8 MB
    unsigned short* hb = (unsigned short*)ws;         ws += (size_t)NN * DD * 2;     // 12.8 MB
    int*   rowptr  = (int*)ws;                        ws += (size_t)(NN + 1) * 4;
    int*   rangeCnt = (int*)ws;                       ws += (size_t)256 * 4;
    int*   rangeBase = (int*)ws;                      ws += (size_t)256 * 4;
    int*   gcur    = (int*)ws;

    const int* src = ei;
    const int* dst = ei + NE;

    // ---- CSR build (ecoarse region reused as xb afterwards) ----
    hipMemsetAsync(rangeCnt, 0, NRANGE * 4, stream);
    hist2_kernel<<<1250, 256, 0, stream>>>(dst, rangeCnt);
    scan196_kernel<<<1, 256, 0, stream>>>(rangeCnt, rangeBase, gcur, rowptr);
    p1_bin_kernel<<<1250, 256, 0, stream>>>(src, dst, w, gcur, ecoarse);
    p2_place_kernel<<<NRANGE, 256, 0, stream>>>(ecoarse, rangeBase, rowptr, ebuf);

    // ---- xb = bf16(x) (ecoarse dead now) ----
    f32_to_bf16_kernel<<<6250, 256, 0, stream>>>(x, xb);

    // ---- Layer 1: gather(xb)->aggb ; mfma([aggb|xb])->hb (bf16, ReLU) ----
    csr_agg_bf16_kernel<<<NN / 4, 256, 0, stream>>>(xb, rowptr, ebuf, aggb);
    mfma_gemm_kernel<true, false><<<GG, 256, 0, stream>>>(
        aggb, xb, Wrel1, brel1, Wroot1, hb);

    // ---- Layer 2: gather(hb)->aggb ; mfma([aggb|hb])->hb (bf16, ReLU) ----
    csr_agg_bf16_kernel<<<NN / 4, 256, 0, stream>>>(hb, rowptr, ebuf, aggb);
    mfma_gemm_kernel<true, false><<<GG, 256, 0, stream>>>(
        aggb, hb, Wrel2, brel2, Wroot2, hb);

    // ---- Layer 3: gather(hb)->aggb ; mfma([aggb|hb])->out (fp32) ----
    csr_agg_bf16_kernel<<<NN / 4, 256, 0, stream>>>(hb, rowptr, ebuf, aggb);
    mfma_gemm_kernel<false, true><<<GG, 256, 0, stream>>>(
        aggb, hb, Wrel3, brel3, Wroot3, out);
}

// Round 2
// 308.449 us; speedup vs baseline: 1.2200x; 1.0607x over previous
//
#include <hip/hip_runtime.h>
#include <hip/hip_bf16.h>

#define NN 100000
#define NE 1280000
#define DD 64
#define RSHIFT 9             // 512-node dst ranges
#define NRANGE 196           // ceil(NN/512)

typedef __attribute__((ext_vector_type(8))) short bf16x8;
typedef __attribute__((ext_vector_type(4))) float f32x4;

static __device__ __forceinline__ unsigned short f2bf(float f) {
    __hip_bfloat16 h = __float2bfloat16(f);
    return *reinterpret_cast<unsigned short*>(&h);
}

// ---------------------------------------------------------------------------
// x (fp32) -> bf16 copy. Grid 6250 x 256, 4 elems/thread (exact: 6.4M).
// ---------------------------------------------------------------------------
__global__ __launch_bounds__(256) void f32_to_bf16_kernel(
    const float* __restrict__ in, unsigned short* __restrict__ out)
{
    int i = (blockIdx.x * 256 + threadIdx.x) * 4;
    float4 v = *(const float4*)(in + i);
    ushort4 o;
    o.x = f2bf(v.x); o.y = f2bf(v.y); o.z = f2bf(v.z); o.w = f2bf(v.w);
    *(ushort4*)(out + i) = o;
}

// ---------------------------------------------------------------------------
// B-fragment pre-pack: Bp[layer][t][256 threads][8] bf16 so the fused GEMM
// loads its 4 ksteps with 4 dwordx4 loads. Grid 3 (one block per layer).
// k = t*32 + quad*8 + j ; n = wv*16 + m16 ; B[k][n] = k<64 ? Wrel : Wroot.
// ---------------------------------------------------------------------------
__global__ __launch_bounds__(256) void bpack_kernel(
    const float* __restrict__ Wrel1, const float* __restrict__ Wroot1,
    const float* __restrict__ Wrel2, const float* __restrict__ Wroot2,
    const float* __restrict__ Wrel3, const float* __restrict__ Wroot3,
    unsigned short* __restrict__ Bp)
{
    int L = blockIdx.x;
    const float* Wrel  = (L == 0) ? Wrel1  : (L == 1) ? Wrel2  : Wrel3;
    const float* Wroot = (L == 0) ? Wroot1 : (L == 1) ? Wroot2 : Wroot3;
    int tid = threadIdx.x;
    int wv = tid >> 6, lane = tid & 63, quad = lane >> 4, m16 = lane & 15;
    int n = wv * 16 + m16;
    unsigned short* o = Bp + (size_t)L * 4 * 256 * 8;
#pragma unroll
    for (int t = 0; t < 4; ++t)
#pragma unroll
        for (int j = 0; j < 8; ++j) {
            int k = t * 32 + quad * 8 + j;
            float wval = (k < 64) ? Wrel[k * 64 + n] : Wroot[(k - 64) * 64 + n];
            o[((size_t)t * 256 + tid) * 8 + j] = f2bf(wval);
        }
}

// ---------------------------------------------------------------------------
// Range histogram: count edges per 512-node dst range. LDS-staged.
// ---------------------------------------------------------------------------
__global__ __launch_bounds__(256) void hist2_kernel(
    const int* __restrict__ dst, int* __restrict__ rangeCnt)
{
    __shared__ int h[256];
    int tid = threadIdx.x;
    h[tid] = 0;
    __syncthreads();
    int e0 = blockIdx.x * 1024 + tid * 4;
    int4 d4 = *(const int4*)(dst + e0);
    atomicAdd(&h[d4.x >> RSHIFT], 1);
    atomicAdd(&h[d4.y >> RSHIFT], 1);
    atomicAdd(&h[d4.z >> RSHIFT], 1);
    atomicAdd(&h[d4.w >> RSHIFT], 1);
    __syncthreads();
    if (tid < NRANGE && h[tid]) atomicAdd(&rangeCnt[tid], h[tid]);
}

// ---------------------------------------------------------------------------
// Exclusive scan of 196 range counts -> rangeBase[197] + gcur (P1 cursors).
// ---------------------------------------------------------------------------
__global__ __launch_bounds__(256) void scan196_kernel(
    const int* __restrict__ rangeCnt, int* __restrict__ rangeBase,
    int* __restrict__ gcur, int* __restrict__ rowptr)
{
    __shared__ int sd[256];
    int tid = threadIdx.x;
    int v = (tid < NRANGE) ? rangeCnt[tid] : 0;
    sd[tid] = v;
    __syncthreads();
    for (int o = 1; o < 256; o <<= 1) {
        int t = (tid >= o) ? sd[tid - o] : 0;
        __syncthreads();
        sd[tid] += t;
        __syncthreads();
    }
    if (tid < NRANGE) { int ex = sd[tid] - v; rangeBase[tid] = ex; gcur[tid] = ex; }
    if (tid == 0) { rangeBase[NRANGE] = NE; rowptr[NN] = NE; }
}

// ---------------------------------------------------------------------------
// P1: coarse bin by dst range, block-synchronous LDS staging (grouped runs).
// Record packs: src (17b) | local-dst (9b @ bit17).
// ---------------------------------------------------------------------------
__global__ __launch_bounds__(256) void p1_bin_kernel(
    const int* __restrict__ src, const int* __restrict__ dst,
    const float* __restrict__ w, int* __restrict__ gcur,
    int2* __restrict__ ecoarse)
{
    __shared__ int2 stage[1024];
    __shared__ unsigned char sbkt[1024];
    __shared__ int cnt[256], ofs[256], gpos[256], sd[256];

    int tid = threadIdx.x;
    int e0 = blockIdx.x * 1024 + tid * 4;
    int4   s4 = *(const int4*)(src + e0);
    int4   d4 = *(const int4*)(dst + e0);
    float4 w4 = *(const float4*)(w + e0);

    cnt[tid] = 0;
    __syncthreads();

    int ss[4] = {s4.x, s4.y, s4.z, s4.w};
    int dd[4] = {d4.x, d4.y, d4.z, d4.w};
    float ww[4] = {w4.x, w4.y, w4.z, w4.w};
    int b[4], p[4];
#pragma unroll
    for (int i = 0; i < 4; ++i) {
        b[i] = dd[i] >> RSHIFT;
        p[i] = atomicAdd(&cnt[b[i]], 1);
    }
    __syncthreads();

    int cv = cnt[tid];
    sd[tid] = cv;
    __syncthreads();
    for (int o = 1; o < 256; o <<= 1) {
        int t = (tid >= o) ? sd[tid - o] : 0;
        __syncthreads();
        sd[tid] += t;
        __syncthreads();
    }
    ofs[tid] = sd[tid] - cv;
    if (tid < NRANGE && cv > 0) gpos[tid] = atomicAdd(&gcur[tid], cv);
    __syncthreads();

#pragma unroll
    for (int i = 0; i < 4; ++i) {
        int slot = ofs[b[i]] + p[i];
        stage[slot] = make_int2(ss[i] | ((dd[i] & 511) << 17), __float_as_int(ww[i]));
        sbkt[slot] = (unsigned char)b[i];
    }
    __syncthreads();

    for (int j = tid; j < 1024; j += 256) {
        int bb = sbkt[j];
        ecoarse[gpos[bb] + (j - ofs[bb])] = stage[j];
    }
}

// ---------------------------------------------------------------------------
// P2: per-range degree count + LDS scan -> rowptr, then place into the
// range's L2-resident ebuf window. Grid NRANGE (196), 2 nodes/thread.
// ---------------------------------------------------------------------------
__global__ __launch_bounds__(256) void p2_place_kernel(
    const int2* __restrict__ ecoarse, const int* __restrict__ rangeBase,
    int* __restrict__ rowptr, int2* __restrict__ ebuf)
{
    __shared__ int cnt[512];
    __shared__ int ssum[256];
    int r = blockIdx.x, tid = threadIdx.x;
    int beg = rangeBase[r], end = rangeBase[r + 1];

    cnt[tid] = 0; cnt[tid + 256] = 0;
    __syncthreads();

    for (int j = beg + tid; j < end; j += 256) {
        int2 rec = ecoarse[j];
        atomicAdd(&cnt[(rec.x >> 17) & 511], 1);
    }
    __syncthreads();

    int c0 = cnt[2 * tid], c1 = cnt[2 * tid + 1];
    int s = c0 + c1;
    ssum[tid] = s;
    __syncthreads();
    for (int o = 1; o < 256; o <<= 1) {
        int t = (tid >= o) ? ssum[tid - o] : 0;
        __syncthreads();
        ssum[tid] += t;
        __syncthreads();
    }
    int p0 = beg + ssum[tid] - s;
    int p1 = p0 + c0;

    int node0 = (r << RSHIFT) + 2 * tid;
    if (node0 < NN)     rowptr[node0]     = p0;
    if (node0 + 1 < NN) rowptr[node0 + 1] = p1;
    cnt[2 * tid] = p0; cnt[2 * tid + 1] = p1;
    __syncthreads();

    for (int j = beg + tid; j < end; j += 256) {
        int2 rec = ecoarse[j];
        int dl = (rec.x >> 17) & 511;
        int p = atomicAdd(&cnt[dl], 1);
        ebuf[p] = make_int2(rec.x & 0x1FFFF, rec.y);
    }
}

// ---------------------------------------------------------------------------
// FUSED layer: CSR gather + dual GEMM + bias (+ReLU) in one kernel.
// Block = 512 thr = 8 waves = 16 nodes (one MFMA m-tile). Half-wave per
// node: 32 lanes = 32 channel pairs (u32 = 2 bf16), one full row per
// edge-load, unroll-8 slots -> 16 gathers in flight per wave. Edges staged
// to regs with one cooperative ebuf load, distributed by __shfl. Agg + root
// rows packed into LDS in MFMA fragment order (pair p = t*16+q*4+jj,
// row = q*16+m), one barrier, waves 0-3 run 4 chained MFMAs + epilogue.
// Ping-pong in/out tables (no in-place hazard).
// ---------------------------------------------------------------------------
template <bool RELU, bool OUT32>
__global__ __launch_bounds__(512) void fused_layer_kernel(
    const unsigned short* __restrict__ hb,   // input node table (gather + root)
    const int* __restrict__ rowptr,
    const int2* __restrict__ ebuf,
    const unsigned short* __restrict__ Bp,   // [4][256][8] bf16 (this layer)
    const float* __restrict__ brel,
    void* __restrict__ outp)
{
    __shared__ __align__(16) unsigned int AstW[4 * 256];   // 4 KB

    int tid = threadIdx.x;
    int lane = tid & 63;
    int wv = tid >> 6;            // 0..7
    int half = lane >> 5;         // node parity within wave
    int ch = lane & 31;           // channel pair
    int base = blockIdx.x * 16;
    int node = base + wv * 2 + half;

    const unsigned int* __restrict__ hw = (const unsigned int*)hb;

    // B fragments + bias preloaded (only used by waves 0-3) so their L2
    // latency hides under the gather.
    bf16x8 bfrag[4];
    float bias = 0.f;
    if (wv < 4) {
#pragma unroll
        for (int t2 = 0; t2 < 4; ++t2)
            bfrag[t2] = *(const bf16x8*)(Bp + ((size_t)t2 * 256 + tid) * 8);
        bias = brel[(wv << 4) | (lane & 15)];
    }

    // root row (own node) issued early
    unsigned rootp = hw[(size_t)node * 32 + ch];

    int beg = rowptr[node];
    int end = rowptr[node + 1];
    int deg = end - beg;

    float aL0 = 0.f, aH0 = 0.f, aL1 = 0.f, aH1 = 0.f;
    for (int c = 0; c < deg; c += 32) {
        int rem = deg - c;
        int nsl = rem < 32 ? rem : 32;
        int idx = (ch < nsl) ? (c + ch) : c;
        int2 e = ebuf[beg + idx];
        float wt = (ch < nsl) ? __int_as_float(e.y) : 0.f;

        for (int s0 = 0; s0 < nsl; s0 += 8) {
#pragma unroll
            for (int i = 0; i < 8; ++i) {
                int slot = s0 + i;
                bool ok = slot < nsl;
                int sl = (half << 5) | (ok ? slot : 0);
                int sr = __shfl(e.x, sl);
                float w = __shfl(wt, sl);
                w = ok ? w : 0.f;
                unsigned v = hw[(size_t)sr * 32 + ch];
                if (i & 1) {
                    aL1 = fmaf(w, __uint_as_float(v << 16), aL1);
                    aH1 = fmaf(w, __uint_as_float(v & 0xFFFF0000u), aH1);
                } else {
                    aL0 = fmaf(w, __uint_as_float(v << 16), aL0);
                    aH0 = fmaf(w, __uint_as_float(v & 0xFFFF0000u), aH0);
                }
            }
        }
    }
    float accL = aL0 + aL1, accH = aH0 + aH1;

    // stage agg (k 0..63) and root (k 64..127) pairs in fragment order
    int m = wv * 2 + half;                     // row 0..15
    int t = ch >> 4, q = (ch >> 2) & 3, jj = ch & 3;
    unsigned pack = ((unsigned)f2bf(accH) << 16) | (unsigned)f2bf(accL);
    AstW[t * 256 + (q * 16 + m) * 4 + jj] = pack;
    AstW[(2 + t) * 256 + (q * 16 + m) * 4 + jj] = rootp;
    __syncthreads();

    if (wv < 4) {
        int quad = lane >> 4, m16 = lane & 15;
        int n = wv * 16 + m16;
        f32x4 cacc = {0.f, 0.f, 0.f, 0.f};
#pragma unroll
        for (int t2 = 0; t2 < 4; ++t2) {
            bf16x8 a = *(const bf16x8*)&AstW[t2 * 256 + lane * 4];
            cacc = __builtin_amdgcn_mfma_f32_16x16x32_bf16(a, bfrag[t2], cacc, 0, 0, 0);
        }
#pragma unroll
        for (int reg = 0; reg < 4; ++reg) {
            int row = quad * 4 + reg;
            size_t onode = (size_t)base + row;
            float v2 = cacc[reg] + bias;
            if (RELU) v2 = fmaxf(v2, 0.f);
            if (OUT32) ((float*)outp)[onode * DD + n] = v2;
            else       ((unsigned short*)outp)[onode * DD + n] = f2bf(v2);
        }
    }
}

extern "C" void kernel_launch(void* const* d_in, const int* in_sizes, int n_in,
                              void* d_out, int out_size, void* d_ws, size_t ws_size,
                              hipStream_t stream)
{
    const float* x     = (const float*)d_in[0];
    const int*   ei    = (const int*)d_in[1];
    const float* w     = (const float*)d_in[2];
    const float* Wrel1 = (const float*)d_in[4];
    const float* brel1 = (const float*)d_in[5];
    const float* Wroot1= (const float*)d_in[6];
    const float* Wrel2 = (const float*)d_in[7];
    const float* brel2 = (const float*)d_in[8];
    const float* Wroot2= (const float*)d_in[9];
    const float* Wrel3 = (const float*)d_in[10];
    const float* brel3 = (const float*)d_in[11];
    const float* Wroot3= (const float*)d_in[12];

    float* out = (float*)d_out;

    // workspace: ebuf | region2 (ecoarse -> xb, after build) | hb1 | hb2 | ints | Bp
    char* ws = (char*)d_ws;
    int2*  ebuf    = (int2*)ws;                       ws += (size_t)NE * 8;          // 10.24 MB
    int2*  ecoarse = (int2*)ws;
    unsigned short* xb = (unsigned short*)ws;         ws += (size_t)NN * DD * 2;     // 12.8 MB (>= ecoarse 10.24)
    unsigned short* hb1 = (unsigned short*)ws;        ws += (size_t)NN * DD * 2;     // 12.8 MB
    unsigned short* hb2 = (unsigned short*)ws;        ws += (size_t)NN * DD * 2;     // 12.8 MB
    int*   rowptr  = (int*)ws;                        ws += (size_t)(NN + 1) * 4;
    int*   rangeCnt = (int*)ws;                       ws += (size_t)256 * 4;
    int*   rangeBase = (int*)ws;                      ws += (size_t)256 * 4;
    int*   gcur    = (int*)ws;                        ws += (size_t)256 * 4;
    unsigned short* Bp = (unsigned short*)ws;         // 3 * 16 KB

    const int* src = ei;
    const int* dst = ei + NE;

    // ---- CSR build (ecoarse region reused as xb afterwards) ----
    hipMemsetAsync(rangeCnt, 0, NRANGE * 4, stream);
    bpack_kernel<<<3, 256, 0, stream>>>(Wrel1, Wroot1, Wrel2, Wroot2, Wrel3, Wroot3, Bp);
    hist2_kernel<<<1250, 256, 0, stream>>>(dst, rangeCnt);
    scan196_kernel<<<1, 256, 0, stream>>>(rangeCnt, rangeBase, gcur, rowptr);
    p1_bin_kernel<<<1250, 256, 0, stream>>>(src, dst, w, gcur, ecoarse);
    p2_place_kernel<<<NRANGE, 256, 0, stream>>>(ecoarse, rangeBase, rowptr, ebuf);

    // ---- xb = bf16(x) (ecoarse dead now) ----
    f32_to_bf16_kernel<<<6250, 256, 0, stream>>>(x, xb);

    // ---- 3 fused layers (ping-pong xb -> hb1 -> hb2 -> out) ----
    fused_layer_kernel<true, false><<<NN / 16, 512, 0, stream>>>(
        xb, rowptr, ebuf, Bp, brel1, hb1);
    fused_layer_kernel<true, false><<<NN / 16, 512, 0, stream>>>(
        hb1, rowptr, ebuf, Bp + (size_t)4 * 256 * 8, brel2, hb2);
    fused_layer_kernel<false, true><<<NN / 16, 512, 0, stream>>>(
        hb2, rowptr, ebuf, Bp + (size_t)8 * 256 * 8, brel3, out);
}